// Round 1
// baseline (446.677 us; speedup 1.0000x reference)
//
#include <hip/hip_runtime.h>

// MomentumSSM: B=2, L=4096, D=512, N=16, R=32, P=64
// Pipeline:
//   k_proj:      projT[b][p][t] = sum_d x[b][t][d] * W_xproj[p][d]     (2 MB)
//   k_dt:        dtT[b][d][t]   = softplus(b_dt[d] + sum_r projT[b][r][t]*W_dt[d][r]) (16 MB)
//   k_transpose: xT[b][d][t]    = x[b][t][d]                            (16 MB)
//   k_scan:      sequential over t; 16 lanes per d (lane=n), 4 d per wave,
//                256 one-wave blocks; float4 double-buffered t-blocks of 16.
//                yT[b][d][t] = sum_n h*C + D[d]*x                        (16 MB)
//   k_transpose: out[b][t][d] = yT[b][d][t]
// ws usage: 52.4 MB total.

#define D_IN 512
#define D_ST 16
#define DTR  32
#define BSZ  2
#define LSEQ 4096
#define PDIM 64

__global__ __launch_bounds__(64) void k_proj(const float* __restrict__ x,
                                             const float* __restrict__ W,
                                             float* __restrict__ projT) {
  __shared__ float xs[8][D_IN];
  const int row0 = blockIdx.x * 8;          // 8 (b,l) rows per block
  const int tid = threadIdx.x;              // p = 0..63
  const float4* xsrc = (const float4*)(x + (size_t)row0 * D_IN);
  float4* xdst = (float4*)&xs[0][0];
#pragma unroll
  for (int i = 0; i < 16; ++i) xdst[tid + 64 * i] = xsrc[tid + 64 * i];
  __syncthreads();
  float acc[8] = {0, 0, 0, 0, 0, 0, 0, 0};
  const float4* Wp4 = (const float4*)(W + tid * D_IN);
  for (int k4 = 0; k4 < D_IN / 4; ++k4) {
    float4 w = Wp4[k4];
#pragma unroll
    for (int r = 0; r < 8; ++r) {
      float4 xv = *(const float4*)&xs[r][k4 * 4];
      acc[r] += w.x * xv.x + w.y * xv.y + w.z * xv.z + w.w * xv.w;
    }
  }
#pragma unroll
  for (int r = 0; r < 8; ++r) {
    int row = row0 + r;
    int b = row >> 12, l = row & (LSEQ - 1);
    projT[((size_t)(b * PDIM + tid)) * LSEQ + l] = acc[r];
  }
}

__global__ __launch_bounds__(256) void k_dt(const float* __restrict__ projT,
                                            const float* __restrict__ W_dt,
                                            const float* __restrict__ b_dt,
                                            float* __restrict__ dtT) {
  __shared__ float Ws[128 * DTR];
  __shared__ float bs[128];
  const int t = blockIdx.x * 256 + threadIdx.x;
  const int d0 = blockIdx.y * 128;
  const int b = blockIdx.z;
  for (int i = threadIdx.x; i < 128 * DTR; i += 256) Ws[i] = W_dt[d0 * DTR + i];
  if (threadIdx.x < 128) bs[threadIdx.x] = b_dt[d0 + threadIdx.x];
  __syncthreads();
  float pv[DTR];
#pragma unroll
  for (int r = 0; r < DTR; ++r) pv[r] = projT[((size_t)(b * PDIM + r)) * LSEQ + t];
  for (int dd = 0; dd < 128; ++dd) {
    float acc = bs[dd];
#pragma unroll
    for (int r = 0; r < DTR; ++r) acc += pv[r] * Ws[dd * DTR + r];
    float sp = (acc > 20.f) ? acc : log1pf(__expf(acc));
    dtT[((size_t)(b * D_IN + d0 + dd)) * LSEQ + t] = sp;
  }
}

// out[b][c][r] = in[b][r][c]; in is [B][R][C]. grid=(R/32, C/32, B), block=(32,8)
__global__ void k_transpose(const float* __restrict__ in, float* __restrict__ out,
                            int R, int C) {
  __shared__ float tile[32][33];
  const int b = blockIdx.z;
  const int r0 = blockIdx.x * 32, c0 = blockIdx.y * 32;
  const float* ip = in + (size_t)b * R * C;
  float* op = out + (size_t)b * R * C;
  const int tx = threadIdx.x, ty = threadIdx.y;
#pragma unroll
  for (int i = 0; i < 32; i += 8) tile[ty + i][tx] = ip[(size_t)(r0 + ty + i) * C + c0 + tx];
  __syncthreads();
#pragma unroll
  for (int i = 0; i < 32; i += 8) op[(size_t)(c0 + ty + i) * R + r0 + tx] = tile[tx][ty + i];
}

struct Blk { float4 q[16]; };  // [0:4)=dt, [4:8)=x, [8:12)=B, [12:16)=C  (16 t-steps)

__device__ inline void load_blk(Blk& o, const float* dtp, const float* xp,
                                const float* Bp, const float* Cp, int t0) {
#pragma unroll
  for (int j = 0; j < 4; ++j) {
    o.q[j]      = *(const float4*)(dtp + t0 + 4 * j);
    o.q[4 + j]  = *(const float4*)(xp + t0 + 4 * j);
    o.q[8 + j]  = *(const float4*)(Bp + t0 + 4 * j);
    o.q[12 + j] = *(const float4*)(Cp + t0 + 4 * j);
  }
}

__global__ __launch_bounds__(64) void k_scan(const float* __restrict__ dtT,
                                             const float* __restrict__ xT,
                                             const float* __restrict__ projT,
                                             const float* __restrict__ A_log,
                                             const float* __restrict__ D_param,
                                             const float* __restrict__ alpha_p,
                                             const float* __restrict__ beta_p,
                                             float* __restrict__ yT) {
  const int lane = threadIdx.x;
  const int grp = lane >> 4, n = lane & 15;
  const int gid = blockIdx.x;               // 0..255
  const int b = gid >> 7;                   // 128 blocks per batch
  const int d = (gid & 127) * 4 + grp;      // 4 d-channels per wave
  const float alpha = alpha_p[0];
  const float beta = 1.f / (1.f + __expf(-beta_p[0]));
  const float A = -__expf(A_log[d * D_ST + n]);
  const float Dv = D_param[d];
  const float* dtp = dtT + ((size_t)(b * D_IN + d)) * LSEQ;
  const float* xp = xT + ((size_t)(b * D_IN + d)) * LSEQ;
  const float* Bp = projT + ((size_t)(b * PDIM + DTR + n)) * LSEQ;
  const float* Cp = projT + ((size_t)(b * PDIM + DTR + D_ST + n)) * LSEQ;
  float* yp = yT + ((size_t)(b * D_IN + d)) * LSEQ;

  float h = 0.f, v = 0.f;
  Blk cur, nxt;
  load_blk(cur, dtp, xp, Bp, Cp, 0);
  for (int t0 = 0; t0 < LSEQ; t0 += 16) {
    const int tn = (t0 + 16) & (LSEQ - 1);  // wraps to 0 on last iter (unused)
    load_blk(nxt, dtp, xp, Bp, Cp, tn);
    const float* cf = (const float*)&cur;
    float ybuf[16];
#pragma unroll
    for (int k = 0; k < 16; ++k) {
      float dtv = cf[k], xv = cf[16 + k], Bv = cf[32 + k], Cv = cf[48 + k];
      float a = __expf(dtv * A);            // A_bar
      float inp = dtv * Bv * xv;
      v = beta * v + alpha * inp;
      h = a * h + v;
      float p = h * Cv;
      p += __shfl_xor(p, 1);
      p += __shfl_xor(p, 2);
      p += __shfl_xor(p, 4);
      p += __shfl_xor(p, 8);
      ybuf[k] = p + Dv * xv;
    }
    if (n == 0) {
#pragma unroll
      for (int j = 0; j < 4; ++j)
        *(float4*)(yp + t0 + 4 * j) =
            make_float4(ybuf[4 * j], ybuf[4 * j + 1], ybuf[4 * j + 2], ybuf[4 * j + 3]);
    }
    cur = nxt;
  }
}

extern "C" void kernel_launch(void* const* d_in, const int* in_sizes, int n_in,
                              void* d_out, int out_size, void* d_ws, size_t ws_size,
                              hipStream_t stream) {
  const float* x          = (const float*)d_in[0];
  const float* A_log      = (const float*)d_in[1];
  const float* D_param    = (const float*)d_in[2];
  const float* W_xproj    = (const float*)d_in[3];
  const float* W_dt       = (const float*)d_in[4];
  const float* b_dt       = (const float*)d_in[5];
  const float* alpha      = (const float*)d_in[6];
  const float* beta_logit = (const float*)d_in[7];
  float* out = (float*)d_out;

  float* ws = (float*)d_ws;
  float* projT = ws;                                   // 2*64*4096   = 524288 floats
  float* dtT   = projT + (size_t)BSZ * PDIM * LSEQ;    // 2*512*4096  = 4194304
  float* xT    = dtT + (size_t)BSZ * D_IN * LSEQ;      // 4194304
  float* yT    = xT + (size_t)BSZ * D_IN * LSEQ;       // 4194304

  k_proj<<<dim3(BSZ * LSEQ / 8), dim3(64), 0, stream>>>(x, W_xproj, projT);
  k_dt<<<dim3(LSEQ / 256, D_IN / 128, BSZ), dim3(256), 0, stream>>>(projT, W_dt, b_dt, dtT);
  k_transpose<<<dim3(LSEQ / 32, D_IN / 32, BSZ), dim3(32, 8), 0, stream>>>(x, xT, LSEQ, D_IN);
  k_scan<<<dim3(256), dim3(64), 0, stream>>>(dtT, xT, projT, A_log, D_param, alpha, beta_logit, yT);
  k_transpose<<<dim3(D_IN / 32, LSEQ / 32, BSZ), dim3(32, 8), 0, stream>>>(yT, out, D_IN, LSEQ);
}

// Round 2
// 266.173 us; speedup vs baseline: 1.6781x; 1.6781x over previous
//
#include <hip/hip_runtime.h>

// MomentumSSM B=2, L=4096, D=512, N=16, R=32, P=64 — chunk-parallel scan.
//
// Layouts (all natural, no transposes):
//   proj[b][l][p]  p=0..31 dt_in, 32..47 B, 48..63 C          (2 MB)
//   dt  [b][l][d]                                             (16 MB)
//   chunk state st = {hhat, vhat, Pa, cv}[b][c][d][n]         (16 MB)
//   init         = {H, V}[b][c][d][n]                         (8 MB)
//
// Recurrence: v_t = beta*v + alpha*inp_t ; h_t = a_t*h + v_t ; a_t=exp(dt*A_n)
// Chunk map:  h_end = Pa*H0 + cv*V0 + hhat ; v_end = beta^Lc*V0 + vhat
//             (cv_j = a_j*cv_{j-1} + beta^j since beta is a scalar constant)

#define D_IN 512
#define D_ST 16
#define DTR  32
#define BSZ  2
#define LSEQ 4096
#define PDIM 64
#define NCH  64
#define LCH  (LSEQ / NCH)

// ---------------- proj = x @ W_xproj^T, natural [row][p] output --------------
__global__ __launch_bounds__(64) void k_proj(const float* __restrict__ x,
                                             const float* __restrict__ W,
                                             float* __restrict__ proj) {
  __shared__ float xs[8][D_IN];
  const int row0 = blockIdx.x * 8;
  const int tid = threadIdx.x;  // p
  const float4* xsrc = (const float4*)(x + (size_t)row0 * D_IN);
  float4* xdst = (float4*)&xs[0][0];
#pragma unroll
  for (int i = 0; i < 16; ++i) xdst[tid + 64 * i] = xsrc[tid + 64 * i];
  __syncthreads();
  float acc[8] = {};
  const float4* Wp4 = (const float4*)(W + tid * D_IN);
  for (int k4 = 0; k4 < D_IN / 4; ++k4) {
    float4 w = Wp4[k4];
#pragma unroll
    for (int r = 0; r < 8; ++r) {
      float4 xv = *(const float4*)&xs[r][k4 * 4];
      acc[r] += w.x * xv.x + w.y * xv.y + w.z * xv.z + w.w * xv.w;
    }
  }
#pragma unroll
  for (int r = 0; r < 8; ++r) proj[(size_t)(row0 + r) * PDIM + tid] = acc[r];
}

// ---------------- dt = softplus(proj[:, :32] @ W_dt^T + b_dt), [row][d] ------
// W_dt row in registers; proj rows are wave-uniform -> scalar loads.
__global__ __launch_bounds__(256) void k_dt(const float* __restrict__ proj,
                                            const float* __restrict__ W_dt,
                                            const float* __restrict__ b_dt,
                                            float* __restrict__ dt) {
  const int r0 = blockIdx.x * 64;                 // flat row base (b*L+l)
  const int d = blockIdx.y * 256 + threadIdx.x;
  float w[DTR];
  const float4* wp = (const float4*)(W_dt + (size_t)d * DTR);
#pragma unroll
  for (int i = 0; i < 8; ++i) ((float4*)w)[i] = wp[i];
  const float bb = b_dt[d];
  for (int r = 0; r < 64; ++r) {
    const float* pr = proj + (size_t)(r0 + r) * PDIM;  // uniform address
    float a0 = bb, a1 = 0.f, a2 = 0.f, a3 = 0.f;
#pragma unroll
    for (int k = 0; k < DTR; k += 4) {
      a0 = fmaf(pr[k + 0], w[k + 0], a0);
      a1 = fmaf(pr[k + 1], w[k + 1], a1);
      a2 = fmaf(pr[k + 2], w[k + 2], a2);
      a3 = fmaf(pr[k + 3], w[k + 3], a3);
    }
    float acc = (a0 + a1) + (a2 + a3);
    float sp = (acc > 20.f) ? acc : log1pf(__expf(acc));
    dt[(size_t)(r0 + r) * D_IN + d] = sp;
  }
}

// ---------------- pass 1: zero-init chunk run + transition accumulation -----
__global__ __launch_bounds__(256) void k_scan1(const float* __restrict__ dt,
                                               const float* __restrict__ x,
                                               const float* __restrict__ proj,
                                               const float* __restrict__ A_log,
                                               const float* __restrict__ alpha_p,
                                               const float* __restrict__ beta_p,
                                               float* __restrict__ st) {
  const int c = blockIdx.x, b = blockIdx.z;
  const int d = blockIdx.y * 256 + threadIdx.x;
  const float alpha = alpha_p[0];
  const float beta = 1.f / (1.f + __expf(-beta_p[0]));
  float A2[D_ST];
  {
    const float4* ap = (const float4*)(A_log + (size_t)d * D_ST);
#pragma unroll
    for (int i = 0; i < 4; ++i) {
      float4 a4 = ap[i];
      A2[4 * i + 0] = -__expf(a4.x) * 1.44269504f;
      A2[4 * i + 1] = -__expf(a4.y) * 1.44269504f;
      A2[4 * i + 2] = -__expf(a4.z) * 1.44269504f;
      A2[4 * i + 3] = -__expf(a4.w) * 1.44269504f;
    }
  }
  float h[16] = {}, v[16] = {}, Pa[16], cv[16] = {};
#pragma unroll
  for (int n = 0; n < 16; ++n) Pa[n] = 1.f;
  float bpow = 1.f;

  const int t0 = c * LCH;
  const float* dtp = dt + (size_t)b * LSEQ * D_IN + d;
  const float* xp = x + (size_t)b * LSEQ * D_IN + d;
  const float* bcp = proj + (size_t)b * LSEQ * PDIM + DTR;  // B at +0..15 (uniform)

  float dcur = dtp[(size_t)t0 * D_IN];
  float xcur = xp[(size_t)t0 * D_IN];
  float4 Bc[4];
#pragma unroll
  for (int i = 0; i < 4; ++i) Bc[i] = *(const float4*)(bcp + (size_t)t0 * PDIM + 4 * i);

  for (int j = 0; j < LCH; ++j) {
    const int tn = t0 + ((j + 1) & (LCH - 1));  // wraps, last prefetch unused
    float dnx = dtp[(size_t)tn * D_IN];
    float xnx = xp[(size_t)tn * D_IN];
    float4 Bn[4];
#pragma unroll
    for (int i = 0; i < 4; ++i) Bn[i] = *(const float4*)(bcp + (size_t)tn * PDIM + 4 * i);

    bpow *= beta;
    const float u = alpha * dcur * xcur;
    const float* Bf = (const float*)Bc;
#pragma unroll
    for (int n = 0; n < 16; ++n) {
      float a = exp2f(dcur * A2[n]);
      v[n] = fmaf(beta, v[n], u * Bf[n]);
      h[n] = fmaf(a, h[n], v[n]);
      Pa[n] *= a;
      cv[n] = fmaf(a, cv[n], bpow);
    }
    dcur = dnx; xcur = xnx;
#pragma unroll
    for (int i = 0; i < 4; ++i) Bc[i] = Bn[i];
  }

  const size_t SZ = (size_t)BSZ * NCH * D_IN * D_ST;
  const size_t base = ((size_t)(b * NCH + c) * D_IN + d) * D_ST;
#pragma unroll
  for (int i = 0; i < 4; ++i) {
    *(float4*)(st + base + 4 * i) = ((float4*)h)[i];
    *(float4*)(st + SZ + base + 4 * i) = ((float4*)v)[i];
    *(float4*)(st + 2 * SZ + base + 4 * i) = ((float4*)Pa)[i];
    *(float4*)(st + 3 * SZ + base + 4 * i) = ((float4*)cv)[i];
  }
}

// ---------------- fixup: sequential scan over 64 chunks ---------------------
__global__ __launch_bounds__(64) void k_fix(const float* __restrict__ st,
                                            const float* __restrict__ beta_p,
                                            float* __restrict__ init) {
  const int g = blockIdx.x * 64 + threadIdx.x;  // (b, d*16+n)
  const int b = g >> 13;
  const int dn = g & 8191;
  const float beta = 1.f / (1.f + __expf(-beta_p[0]));
  float bL = beta;
#pragma unroll
  for (int i = 0; i < 6; ++i) bL *= bL;  // beta^64
  const size_t SZ = (size_t)BSZ * NCH * D_IN * D_ST;
  const float* hh = st;
  const float* vh = st + SZ;
  const float* Pp = st + 2 * SZ;
  const float* cp = st + 3 * SZ;
  float* Hi = init;
  float* Vi = init + SZ;
  float H = 0.f, V = 0.f;
  for (int c = 0; c < NCH; ++c) {
    const size_t idx = (size_t)(b * NCH + c) * (D_IN * D_ST) + dn;
    Hi[idx] = H;
    Vi[idx] = V;
    float Pv = Pp[idx], cvv = cp[idx], hhv = hh[idx], vhv = vh[idx];
    H = fmaf(Pv, H, fmaf(cvv, V, hhv));
    V = fmaf(bL, V, vhv);
  }
}

// ---------------- pass 2: correct-init chunk run, emit y --------------------
__global__ __launch_bounds__(256) void k_scan2(const float* __restrict__ dt,
                                               const float* __restrict__ x,
                                               const float* __restrict__ proj,
                                               const float* __restrict__ A_log,
                                               const float* __restrict__ D_param,
                                               const float* __restrict__ alpha_p,
                                               const float* __restrict__ beta_p,
                                               const float* __restrict__ init,
                                               float* __restrict__ out) {
  const int c = blockIdx.x, b = blockIdx.z;
  const int d = blockIdx.y * 256 + threadIdx.x;
  const float alpha = alpha_p[0];
  const float beta = 1.f / (1.f + __expf(-beta_p[0]));
  const float Dv = D_param[d];
  float A2[D_ST];
  {
    const float4* ap = (const float4*)(A_log + (size_t)d * D_ST);
#pragma unroll
    for (int i = 0; i < 4; ++i) {
      float4 a4 = ap[i];
      A2[4 * i + 0] = -__expf(a4.x) * 1.44269504f;
      A2[4 * i + 1] = -__expf(a4.y) * 1.44269504f;
      A2[4 * i + 2] = -__expf(a4.z) * 1.44269504f;
      A2[4 * i + 3] = -__expf(a4.w) * 1.44269504f;
    }
  }
  const size_t SZ = (size_t)BSZ * NCH * D_IN * D_ST;
  const size_t ibase = ((size_t)(b * NCH + c) * D_IN + d) * D_ST;
  float h[16], v[16];
#pragma unroll
  for (int i = 0; i < 4; ++i) {
    ((float4*)h)[i] = *(const float4*)(init + ibase + 4 * i);
    ((float4*)v)[i] = *(const float4*)(init + SZ + ibase + 4 * i);
  }

  const int t0 = c * LCH;
  const float* dtp = dt + (size_t)b * LSEQ * D_IN + d;
  const float* xp = x + (size_t)b * LSEQ * D_IN + d;
  const float* bcp = proj + (size_t)b * LSEQ * PDIM + DTR;  // B at +0..15, C at +16..31
  float* op = out + (size_t)b * LSEQ * D_IN + d;

  float dcur = dtp[(size_t)t0 * D_IN];
  float xcur = xp[(size_t)t0 * D_IN];
  float4 BCc[8];
#pragma unroll
  for (int i = 0; i < 8; ++i) BCc[i] = *(const float4*)(bcp + (size_t)t0 * PDIM + 4 * i);

  for (int j = 0; j < LCH; ++j) {
    const int t = t0 + j;
    const int tn = t0 + ((j + 1) & (LCH - 1));
    float dnx = dtp[(size_t)tn * D_IN];
    float xnx = xp[(size_t)tn * D_IN];
    float4 BCn[8];
#pragma unroll
    for (int i = 0; i < 8; ++i) BCn[i] = *(const float4*)(bcp + (size_t)tn * PDIM + 4 * i);

    const float u = alpha * dcur * xcur;
    const float* Bf = (const float*)BCc;        // [0:16) = B, [16:32) = C
    float y0 = 0.f, y1 = 0.f, y2 = 0.f, y3 = 0.f;
#pragma unroll
    for (int n = 0; n < 16; ++n) {
      float a = exp2f(dcur * A2[n]);
      v[n] = fmaf(beta, v[n], u * Bf[n]);
      h[n] = fmaf(a, h[n], v[n]);
      float hc = h[n] * Bf[16 + n];
      if ((n & 3) == 0) y0 += hc;
      else if ((n & 3) == 1) y1 += hc;
      else if ((n & 3) == 2) y2 += hc;
      else y3 += hc;
    }
    op[(size_t)t * D_IN] = (y0 + y1) + (y2 + y3) + Dv * xcur;
    dcur = dnx; xcur = xnx;
#pragma unroll
    for (int i = 0; i < 8; ++i) BCc[i] = BCn[i];
  }
}

extern "C" void kernel_launch(void* const* d_in, const int* in_sizes, int n_in,
                              void* d_out, int out_size, void* d_ws, size_t ws_size,
                              hipStream_t stream) {
  const float* x = (const float*)d_in[0];
  const float* A_log = (const float*)d_in[1];
  const float* D_param = (const float*)d_in[2];
  const float* W_xproj = (const float*)d_in[3];
  const float* W_dt = (const float*)d_in[4];
  const float* b_dt = (const float*)d_in[5];
  const float* alpha = (const float*)d_in[6];
  const float* beta_logit = (const float*)d_in[7];
  float* out = (float*)d_out;

  float* ws = (float*)d_ws;
  float* proj = ws;                                       // 524288 floats (2 MB)
  float* dt = proj + (size_t)BSZ * LSEQ * PDIM;           // 4194304 (16 MB)
  float* st = dt + (size_t)BSZ * LSEQ * D_IN;             // 4 x 1048576 (16 MB)
  float* init = st + 4 * (size_t)BSZ * NCH * D_IN * D_ST; // 2 x 1048576 (8 MB)

  k_proj<<<dim3(BSZ * LSEQ / 8), dim3(64), 0, stream>>>(x, W_xproj, proj);
  k_dt<<<dim3(BSZ * LSEQ / 64, D_IN / 256), dim3(256), 0, stream>>>(proj, W_dt, b_dt, dt);
  k_scan1<<<dim3(NCH, D_IN / 256, BSZ), dim3(256), 0, stream>>>(dt, x, proj, A_log, alpha,
                                                                beta_logit, st);
  k_fix<<<dim3(BSZ * D_IN * D_ST / 64), dim3(64), 0, stream>>>(st, beta_logit, init);
  k_scan2<<<dim3(NCH, D_IN / 256, BSZ), dim3(256), 0, stream>>>(dt, x, proj, A_log, D_param,
                                                                alpha, beta_logit, init, out);
}